// Round 1
// baseline (1252.939 us; speedup 1.0000x reference)
//
#include <hip/hip_runtime.h>
#include <cstdint>

typedef unsigned short u16;
typedef unsigned int   u32;
typedef __attribute__((ext_vector_type(8))) short bf16x8;   // 8 bf16 = 4 VGPRs
typedef __attribute__((ext_vector_type(4))) float f32x4;

#define MFMA16(a,b,c) __builtin_amdgcn_mfma_f32_16x16x32_bf16((a),(b),(c),0,0,0)

#define BSZ    4
#define SEQ    2048
#define DMODEL 1024
#define NHEAD  16
#define HDIM   64
#define MTOT   (BSZ*SEQ)   // 8192

__device__ __forceinline__ u16 f2bf(float f) {
  u32 u = __float_as_uint(f);
  u32 r = u + 0x7fffu + ((u >> 16) & 1u);   // RNE
  return (u16)(r >> 16);
}

typedef __attribute__((address_space(1))) void g1v;
typedef __attribute__((address_space(3))) void l3v;
// async global->LDS, 16B/lane. LDS dest must be wave-uniform base (HW adds lane*16B).
__device__ __forceinline__ void gload16(const void* g, void* l) {
  __builtin_amdgcn_global_load_lds((g1v*)(uintptr_t)g, (l3v*)(u32)(uintptr_t)l, 16, 0, 0);
}

// ---------------- pack: fp32 -> bf16 activations ----------------
__global__ void pack_act(const float* __restrict__ in, u16* __restrict__ out, int n4) {
  int i = blockIdx.x * blockDim.x + threadIdx.x;
  if (i >= n4) return;
  float4 v = ((const float4*)in)[i];
  u32 lo = (u32)f2bf(v.x) | ((u32)f2bf(v.y) << 16);
  u32 hi = (u32)f2bf(v.z) | ((u32)f2bf(v.w) << 16);
  ((uint2*)out)[i] = make_uint2(lo, hi);
}

// ---------------- pack: weights -> Bt[n][k] bf16 (transposed) ----------------
// per_head=1: src is [H][D][HD], column n = h*64+e -> Bt[n][k] = src[n>>6][k][n&63]
// per_head=0: src is [D][D] row-major        -> Bt[n][k] = src[k][n]
__global__ void pack_w(const float* __restrict__ src, u16* __restrict__ dst, int per_head) {
  __shared__ float tile[64][65];
  int kt = blockIdx.x * 64, nt = blockIdx.y * 64;
  int tx = threadIdx.x & 63, ty = threadIdx.x >> 6;
  for (int kk = ty; kk < 64; kk += 4) {
    int k = kt + kk, n = nt + tx;
    float v = per_head ? src[(size_t)(n >> 6) * (DMODEL * HDIM) + (size_t)k * HDIM + (n & 63)]
                       : src[(size_t)k * DMODEL + n];
    tile[kk][tx] = v;
  }
  __syncthreads();
  for (int nn = ty; nn < 64; nn += 4)
    dst[(size_t)(nt + nn) * DMODEL + kt + tx] = f2bf(tile[tx][nn]);
}

// ---------------- GEMM: C[M,N] = A[M,K] @ Bt[N,K]^T + bias ----------------
// m97 structure: 128x128 tile, BK=32, 4 waves (2x2 of 64x64), global_load_lds(16B).
// EPI 0: bf16 [M][N];  1: bf16 transposed V layout Vt[(b*16+h)*64+e][s];  2: f32 [M][N]
template <int EPI>
__global__ __launch_bounds__(256, 2)
void gemm_bt(const u16* __restrict__ A, const u16* __restrict__ Bt,
             const float* __restrict__ bias, void* __restrict__ Cout)
{
  __shared__ u16 As[128 * 32];
  __shared__ u16 Bs[128 * 32];
  const int lane = threadIdx.x & 63, wid = threadIdx.x >> 6;
  const int m0 = blockIdx.y * 128, n0 = blockIdx.x * 128;

  // staging: wave w covers rows w*32..w*32+31; one instr = 16 rows x 64B
  const int srow = wid * 32 + (lane >> 2);
  const int scol = (lane & 3) * 8;
  const u16* gA = A  + (size_t)(m0 + srow) * DMODEL + scol;
  const u16* gB = Bt + (size_t)(n0 + srow) * DMODEL + scol;
  u16* lA0 = &As[(wid * 32) * 32];
  u16* lA1 = &As[(wid * 32 + 16) * 32];
  u16* lB0 = &Bs[(wid * 32) * 32];
  u16* lB1 = &Bs[(wid * 32 + 16) * 32];

  const int fr = lane & 15, quad = lane >> 4, fk = quad * 8;
  const int wr = (wid >> 1) * 64, wc = (wid & 1) * 64;

  f32x4 acc[4][4] = {};

  for (int kt = 0; kt < DMODEL / 32; ++kt) {
    __syncthreads();                       // LDS free from previous step
    gload16(gA,              lA0);
    gload16(gA + 16 * DMODEL, lA1);
    gload16(gB,              lB0);
    gload16(gB + 16 * DMODEL, lB1);
    gA += 32; gB += 32;
    __syncthreads();                       // drains vmcnt(0) -> tiles ready

    bf16x8 af[4], bfr[4];
#pragma unroll
    for (int i = 0; i < 4; ++i) {
      af[i]  = *(const bf16x8*)&As[(wr + i * 16 + fr) * 32 + fk];
      bfr[i] = *(const bf16x8*)&Bs[(wc + i * 16 + fr) * 32 + fk];
    }
#pragma unroll
    for (int i = 0; i < 4; ++i)
#pragma unroll
      for (int j = 0; j < 4; ++j)
        acc[i][j] = MFMA16(af[i], bfr[j], acc[i][j]);
  }

  // C/D layout: col = lane&15, row = (lane>>4)*4 + reg  (HW-verified)
#pragma unroll
  for (int i = 0; i < 4; ++i) {
    int row0 = m0 + wr + i * 16 + quad * 4;
#pragma unroll
    for (int j = 0; j < 4; ++j) {
      int col = n0 + wc + j * 16 + fr;
      float bv = bias[col];
      float v0 = acc[i][j][0] + bv, v1 = acc[i][j][1] + bv;
      float v2 = acc[i][j][2] + bv, v3 = acc[i][j][3] + bv;
      if constexpr (EPI == 2) {
        float* C = (float*)Cout;
        C[(size_t)(row0 + 0) * DMODEL + col] = v0;
        C[(size_t)(row0 + 1) * DMODEL + col] = v1;
        C[(size_t)(row0 + 2) * DMODEL + col] = v2;
        C[(size_t)(row0 + 3) * DMODEL + col] = v3;
      } else if constexpr (EPI == 0) {
        u16* C = (u16*)Cout;
        C[(size_t)(row0 + 0) * DMODEL + col] = f2bf(v0);
        C[(size_t)(row0 + 1) * DMODEL + col] = f2bf(v1);
        C[(size_t)(row0 + 2) * DMODEL + col] = f2bf(v2);
        C[(size_t)(row0 + 3) * DMODEL + col] = f2bf(v3);
      } else {
        // Vt[(b*16 + h)*64 + e][s]; 4 consecutive s -> one 8B store
        u16* C = (u16*)Cout;
        int bi = row0 >> 11, s = row0 & 2047;
        size_t vtr = ((size_t)(bi * NHEAD + (col >> 6)) * HDIM + (col & 63)) * SEQ + s;
        *(uint2*)&C[vtr] = make_uint2((u32)f2bf(v0) | ((u32)f2bf(v1) << 16),
                                      (u32)f2bf(v2) | ((u32)f2bf(v3) << 16));
      }
    }
  }
}

// ---------------- flash attention ----------------
// grid: (SEQ/64, B*H). 4 waves/block, each wave owns 16 q-rows independently.
// Q,K: [B*S][1024] bf16 (head slice at col h*64). Vt: [(b*16+h)*64+d][s] bf16.
__global__ __launch_bounds__(256, 2)
void attn_kernel(const u16* __restrict__ Q, const u16* __restrict__ K,
                 const u16* __restrict__ Vt, u16* __restrict__ O, int causal)
{
  __shared__ u16 plds[4][16][32];
  const int lane = threadIdx.x & 63, wid = threadIdx.x >> 6;
  const int fr = lane & 15, quad = lane >> 4;
  const int bh = blockIdx.y, b = bh >> 4, h = bh & 15;
  const int q0 = blockIdx.x * 64 + wid * 16;

  const u16* qp = Q + (size_t)(b * SEQ + q0 + fr) * DMODEL + h * HDIM + quad * 8;
  bf16x8 aq0 = *(const bf16x8*)qp;
  bf16x8 aq1 = *(const bf16x8*)(qp + 32);

  const u16* kbase = K + (size_t)(b * SEQ + fr) * DMODEL + h * HDIM + quad * 8;
  const u16* vbase = Vt + ((size_t)bh * HDIM + fr) * SEQ + quad * 8;

  f32x4 oacc[4] = {};
  float mrow[4] = {-1e30f, -1e30f, -1e30f, -1e30f};
  float lrow[4] = {0.f, 0.f, 0.f, 0.f};
  float al[4];

  const int nk = causal ? (q0 + 16) : SEQ;
  for (int kb = 0; kb < nk; kb += 32) {
    // QK^T: S[q][key], two 16-key sub-blocks
    const u16* kp = kbase + (size_t)kb * DMODEL;
    bf16x8 k00 = *(const bf16x8*)kp;
    bf16x8 k01 = *(const bf16x8*)(kp + 32);
    bf16x8 k10 = *(const bf16x8*)(kp + (size_t)16 * DMODEL);
    bf16x8 k11 = *(const bf16x8*)(kp + (size_t)16 * DMODEL + 32);
    f32x4 sa0 = {}, sa1 = {};
    sa0 = MFMA16(aq0, k00, sa0);
    sa0 = MFMA16(aq1, k01, sa0);
    sa1 = MFMA16(aq0, k10, sa1);
    sa1 = MFMA16(aq1, k11, sa1);

#pragma unroll
    for (int r = 0; r < 4; ++r) {
      float s0 = sa0[r] * 0.125f, s1 = sa1[r] * 0.125f;
      if (causal) {
        int q = q0 + quad * 4 + r;
        if (kb + fr > q)      s0 = -1e30f;
        if (kb + 16 + fr > q) s1 = -1e30f;
      }
      float mx = fmaxf(s0, s1);
      mx = fmaxf(mx, __shfl_xor(mx, 1));
      mx = fmaxf(mx, __shfl_xor(mx, 2));
      mx = fmaxf(mx, __shfl_xor(mx, 4));
      mx = fmaxf(mx, __shfl_xor(mx, 8));
      float mnew = fmaxf(mrow[r], mx);
      float a = __expf(mrow[r] - mnew);
      mrow[r] = mnew;
      float p0 = __expf(s0 - mnew), p1 = __expf(s1 - mnew);
      float ps = p0 + p1;
      ps += __shfl_xor(ps, 1);
      ps += __shfl_xor(ps, 2);
      ps += __shfl_xor(ps, 4);
      ps += __shfl_xor(ps, 8);
      lrow[r] = lrow[r] * a + ps;
      al[r] = a;
      plds[wid][quad * 4 + r][fr]      = f2bf(p0);
      plds[wid][quad * 4 + r][16 + fr] = f2bf(p1);
    }
#pragma unroll
    for (int n = 0; n < 4; ++n) {
      oacc[n][0] *= al[0]; oacc[n][1] *= al[1];
      oacc[n][2] *= al[2]; oacc[n][3] *= al[3];
    }
    // cross-lane P handoff through per-wave LDS: fence hw + compiler
    asm volatile("s_waitcnt lgkmcnt(0)" ::: "memory");
    bf16x8 pa = *(const bf16x8*)&plds[wid][fr][quad * 8];
    const u16* vp = vbase + kb;
#pragma unroll
    for (int n = 0; n < 4; ++n) {
      bf16x8 vf = *(const bf16x8*)(vp + (size_t)n * 16 * SEQ);
      oacc[n] = MFMA16(pa, vf, oacc[n]);
    }
  }

  u16* op = O + (size_t)(b * SEQ + q0 + quad * 4) * DMODEL + h * HDIM + fr;
#pragma unroll
  for (int r = 0; r < 4; ++r) {
    float inv = 1.0f / lrow[r];
#pragma unroll
    for (int n = 0; n < 4; ++n)
      op[(size_t)r * DMODEL + n * 16] = f2bf(oacc[n][r] * inv);
  }
}

// ---------------- launcher ----------------
extern "C" void kernel_launch(void* const* d_in, const int* in_sizes, int n_in,
                              void* d_out, int out_size, void* d_ws, size_t ws_size,
                              hipStream_t stream)
{
  const float* x   = (const float*)d_in[0];
  const float* ek  = (const float*)d_in[1];
  const float* ev  = (const float*)d_in[2];
  const float* Wq1 = (const float*)d_in[3];
  const float* bq1 = (const float*)d_in[4];
  const float* Wk1 = (const float*)d_in[5];
  const float* bk1 = (const float*)d_in[6];
  const float* Wv1 = (const float*)d_in[7];
  const float* bv1 = (const float*)d_in[8];
  const float* Wo1 = (const float*)d_in[9];
  const float* bo1 = (const float*)d_in[10];
  const float* Wq2 = (const float*)d_in[11];
  const float* bq2 = (const float*)d_in[12];
  const float* Wk2 = (const float*)d_in[13];
  const float* bk2 = (const float*)d_in[14];
  const float* Wv2 = (const float*)d_in[15];
  const float* bv2 = (const float*)d_in[16];
  const float* Wo2 = (const float*)d_in[17];
  const float* bo2 = (const float*)d_in[18];

  // ws layout (128 MB total):
  // [0,16M)   8x packed bf16 weights Bt[1024][1024]
  // [16,32M)  xb   (x bf16)          -- reused as attention output `ob`
  // [32,48M)  ekb  [48,64M) evb
  // [64,80M)  qb   [80,96M) kb   [96,112M) vtb   [112,128M) hb
  char* ws = (char*)d_ws;
  u16* wt  = (u16*)ws;
  u16* xb  = (u16*)(ws + (16u << 20));
  u16* ekb = (u16*)(ws + (32u << 20));
  u16* evb = (u16*)(ws + (48u << 20));
  u16* qb  = (u16*)(ws + (64u << 20));
  u16* kkb = (u16*)(ws + (80u << 20));
  u16* vtb = (u16*)(ws + (96u << 20));
  u16* hb  = (u16*)(ws + (112u << 20));
  u16* ob  = xb;   // x is dead once Q1/K1/V1 projections complete

  const int NW = DMODEL * DMODEL;          // elems per packed weight
  const int n4 = MTOT * DMODEL / 4;        // float4 count per activation

  pack_act<<<n4 / 256, 256, 0, stream>>>(x,  xb,  n4);
  pack_act<<<n4 / 256, 256, 0, stream>>>(ek, ekb, n4);
  pack_act<<<n4 / 256, 256, 0, stream>>>(ev, evb, n4);

  dim3 wg(16, 16);
  pack_w<<<wg, 256, 0, stream>>>(Wq1, wt + 0 * NW, 1);
  pack_w<<<wg, 256, 0, stream>>>(Wk1, wt + 1 * NW, 1);
  pack_w<<<wg, 256, 0, stream>>>(Wv1, wt + 2 * NW, 1);
  pack_w<<<wg, 256, 0, stream>>>(Wo1, wt + 3 * NW, 0);
  pack_w<<<wg, 256, 0, stream>>>(Wq2, wt + 4 * NW, 1);
  pack_w<<<wg, 256, 0, stream>>>(Wk2, wt + 5 * NW, 1);
  pack_w<<<wg, 256, 0, stream>>>(Wv2, wt + 6 * NW, 1);
  pack_w<<<wg, 256, 0, stream>>>(Wo2, wt + 7 * NW, 0);

  dim3 gg(DMODEL / 128, MTOT / 128);   // (8, 64)
  dim3 ag(SEQ / 64, BSZ * NHEAD);      // (32, 64)

  // layer 1: causal self-attention
  gemm_bt<0><<<gg, 256, 0, stream>>>(xb,  wt + 0 * NW, bq1, qb);
  gemm_bt<0><<<gg, 256, 0, stream>>>(xb,  wt + 1 * NW, bk1, kkb);
  gemm_bt<1><<<gg, 256, 0, stream>>>(xb,  wt + 2 * NW, bv1, vtb);
  attn_kernel<<<ag, 256, 0, stream>>>(qb, kkb, vtb, ob, 1);
  gemm_bt<0><<<gg, 256, 0, stream>>>(ob,  wt + 3 * NW, bo1, hb);

  // layer 2: cross attention (K/V from encoder)
  gemm_bt<0><<<gg, 256, 0, stream>>>(hb,  wt + 4 * NW, bq2, qb);
  gemm_bt<0><<<gg, 256, 0, stream>>>(ekb, wt + 5 * NW, bk2, kkb);
  gemm_bt<1><<<gg, 256, 0, stream>>>(evb, wt + 6 * NW, bv2, vtb);
  attn_kernel<<<ag, 256, 0, stream>>>(qb, kkb, vtb, ob, 0);
  gemm_bt<2><<<gg, 256, 0, stream>>>(ob,  wt + 7 * NW, bo2, d_out);
}

// Round 2
// 673.012 us; speedup vs baseline: 1.8617x; 1.8617x over previous
//
#include <hip/hip_runtime.h>
#include <cstdint>

typedef unsigned short u16;
typedef unsigned int   u32;
typedef __attribute__((ext_vector_type(8))) short bf16x8;   // 8 bf16 = 4 VGPRs
typedef __attribute__((ext_vector_type(4))) float f32x4;

#define MFMA16(a,b,c) __builtin_amdgcn_mfma_f32_16x16x32_bf16((a),(b),(c),0,0,0)

#define BSZ    4
#define SEQ    2048
#define DMODEL 1024
#define NHEAD  16
#define HDIM   64
#define MTOT   (BSZ*SEQ)   // 8192

__device__ __forceinline__ u16 f2bf(float f) {
  u32 u = __float_as_uint(f);
  u32 r = u + 0x7fffu + ((u >> 16) & 1u);   // RNE
  return (u16)(r >> 16);
}

typedef __attribute__((address_space(1))) void g1v;
typedef __attribute__((address_space(3))) void l3v;
// async global->LDS, 16B/lane. LDS dest is wave-uniform base (HW adds lane*16B).
__device__ __forceinline__ void gload16(const void* g, void* l) {
  __builtin_amdgcn_global_load_lds((g1v*)(uintptr_t)g, (l3v*)(u32)(uintptr_t)l, 16, 0, 0);
}

// ---------------- pack: fp32 -> bf16 activations ----------------
__global__ void pack_act(const float* __restrict__ in, u16* __restrict__ out, int n4) {
  int i = blockIdx.x * blockDim.x + threadIdx.x;
  if (i >= n4) return;
  float4 v = ((const float4*)in)[i];
  u32 lo = (u32)f2bf(v.x) | ((u32)f2bf(v.y) << 16);
  u32 hi = (u32)f2bf(v.z) | ((u32)f2bf(v.w) << 16);
  ((uint2*)out)[i] = make_uint2(lo, hi);
}

// ---------------- pack: weights -> Bt[n][k] bf16 (transposed) ----------------
__global__ void pack_w(const float* __restrict__ src, u16* __restrict__ dst, int per_head) {
  __shared__ float tile[64][65];
  int kt = blockIdx.x * 64, nt = blockIdx.y * 64;
  int tx = threadIdx.x & 63, ty = threadIdx.x >> 6;
  for (int kk = ty; kk < 64; kk += 4) {
    int k = kt + kk, n = nt + tx;
    float v = per_head ? src[(size_t)(n >> 6) * (DMODEL * HDIM) + (size_t)k * HDIM + (n & 63)]
                       : src[(size_t)k * DMODEL + n];
    tile[kk][tx] = v;
  }
  __syncthreads();
  for (int nn = ty; nn < 64; nn += 4)
    dst[(size_t)(nt + nn) * DMODEL + kt + tx] = f2bf(tile[tx][nn]);
}

// ---------------- GEMM: C[M,N] = (A[M,K] @ Bt[N,K]^T + bias) * scale ----------------
// m97 structure: 128x128 tile, BK=32, 4 waves, global_load_lds(16B).
// EPI 0: bf16 [M][N]; 1: bf16 Vt[(b*16+h)*64+e][s]; 2: f32 [M][N]
template <int EPI>
__global__ __launch_bounds__(256, 2)
void gemm_bt(const u16* __restrict__ A, const u16* __restrict__ Bt,
             const float* __restrict__ bias, void* __restrict__ Cout, float scale)
{
  __shared__ u16 As[128 * 32];
  __shared__ u16 Bs[128 * 32];
  const int lane = threadIdx.x & 63, wid = threadIdx.x >> 6;
  const int m0 = blockIdx.y * 128, n0 = blockIdx.x * 128;

  const int srow = wid * 32 + (lane >> 2);
  const int scol = (lane & 3) * 8;
  const u16* gA = A  + (size_t)(m0 + srow) * DMODEL + scol;
  const u16* gB = Bt + (size_t)(n0 + srow) * DMODEL + scol;
  u16* lA0 = &As[(wid * 32) * 32];
  u16* lA1 = &As[(wid * 32 + 16) * 32];
  u16* lB0 = &Bs[(wid * 32) * 32];
  u16* lB1 = &Bs[(wid * 32 + 16) * 32];

  const int fr = lane & 15, quad = lane >> 4, fk = quad * 8;
  const int wr = (wid >> 1) * 64, wc = (wid & 1) * 64;

  f32x4 acc[4][4] = {};

  for (int kt = 0; kt < DMODEL / 32; ++kt) {
    __syncthreads();
    gload16(gA,               lA0);
    gload16(gA + 16 * DMODEL, lA1);
    gload16(gB,               lB0);
    gload16(gB + 16 * DMODEL, lB1);
    gA += 32; gB += 32;
    __syncthreads();

    bf16x8 af[4], bfr[4];
#pragma unroll
    for (int i = 0; i < 4; ++i) {
      af[i]  = *(const bf16x8*)&As[(wr + i * 16 + fr) * 32 + fk];
      bfr[i] = *(const bf16x8*)&Bs[(wc + i * 16 + fr) * 32 + fk];
    }
#pragma unroll
    for (int i = 0; i < 4; ++i)
#pragma unroll
      for (int j = 0; j < 4; ++j)
        acc[i][j] = MFMA16(af[i], bfr[j], acc[i][j]);
  }

  // C/D layout: col = lane&15, row = (lane>>4)*4 + reg
#pragma unroll
  for (int i = 0; i < 4; ++i) {
    int row0 = m0 + wr + i * 16 + quad * 4;
#pragma unroll
    for (int j = 0; j < 4; ++j) {
      int col = n0 + wc + j * 16 + fr;
      float bv = bias[col];
      float v0 = (acc[i][j][0] + bv) * scale, v1 = (acc[i][j][1] + bv) * scale;
      float v2 = (acc[i][j][2] + bv) * scale, v3 = (acc[i][j][3] + bv) * scale;
      if constexpr (EPI == 2) {
        float* C = (float*)Cout;
        C[(size_t)(row0 + 0) * DMODEL + col] = v0;
        C[(size_t)(row0 + 1) * DMODEL + col] = v1;
        C[(size_t)(row0 + 2) * DMODEL + col] = v2;
        C[(size_t)(row0 + 3) * DMODEL + col] = v3;
      } else if constexpr (EPI == 0) {
        u16* C = (u16*)Cout;
        C[(size_t)(row0 + 0) * DMODEL + col] = f2bf(v0);
        C[(size_t)(row0 + 1) * DMODEL + col] = f2bf(v1);
        C[(size_t)(row0 + 2) * DMODEL + col] = f2bf(v2);
        C[(size_t)(row0 + 3) * DMODEL + col] = f2bf(v3);
      } else {
        u16* C = (u16*)Cout;
        int bi = row0 >> 11, s = row0 & 2047;
        size_t vtr = ((size_t)(bi * NHEAD + (col >> 6)) * HDIM + (col & 63)) * SEQ + s;
        *(uint2*)&C[vtr] = make_uint2((u32)f2bf(v0) | ((u32)f2bf(v1) << 16),
                                      (u32)f2bf(v2) | ((u32)f2bf(v3) << 16));
      }
    }
  }
}

// ---------------- flash attention v2 ----------------
// grid (SEQ/64, B*H), 4 waves/block sharing (b,h) and a 64-q block; wave owns 16 q-rows.
// KVBLK=64, double-buffered LDS K/V staged via global_load_lds with pre-swizzled source.
// Swizzle: 16B chunk j of row r lives at LDS chunk j^(r&7) (involution; 2-way = free).
// Q pre-scaled by 0.125*log2(e) in projection; softmax in exp2 domain.
__global__ __launch_bounds__(256, 3)
void attn_kernel(const u16* __restrict__ Q, const u16* __restrict__ K,
                 const u16* __restrict__ Vt, u16* __restrict__ O, int causal)
{
  __shared__ u16 Ks[2][64 * 64];   // [key][dim], swizzled
  __shared__ u16 Vs[2][64 * 64];   // [d][s_local], swizzled
  __shared__ u16 plds[4][16 * 64]; // per-wave P [q][key], swizzled
  const int lane = threadIdx.x & 63, wid = threadIdx.x >> 6;
  const int fr = lane & 15, quad = lane >> 4;
  const int bh = blockIdx.y, b = bh >> 4, h = bh & 15;
  const int q0 = blockIdx.x * 64;
  const int qw = q0 + wid * 16;

  const u16* qp = Q + (size_t)(b * SEQ + qw + fr) * DMODEL + h * HDIM + quad * 8;
  bf16x8 aq0 = *(const bf16x8*)qp;
  bf16x8 aq1 = *(const bf16x8*)(qp + 32);

  const int srow = wid * 16 + (lane >> 3);  // + i*8
  const int jl = lane & 7;
  const u16* kg = K + (size_t)b * SEQ * DMODEL + h * HDIM;
  const u16* vg = Vt + (size_t)bh * HDIM * SEQ;

  f32x4 oacc[4] = {};
  f32x4 sa[4];
  float mrow[4] = {-1e30f, -1e30f, -1e30f, -1e30f};
  float lrow[4] = {0.f, 0.f, 0.f, 0.f};

  const int nsteps = (causal ? (q0 + 64) : SEQ) >> 6;

#pragma unroll
  for (int i = 0; i < 2; ++i) {
    int r2 = srow + i * 8;
    int jg = jl ^ (r2 & 7);
    gload16(kg + (size_t)r2 * DMODEL + jg * 8, &Ks[0][(wid * 16 + i * 8) * 64]);
    gload16(vg + (size_t)r2 * SEQ + jg * 8,    &Vs[0][(wid * 16 + i * 8) * 64]);
  }
  __syncthreads();

  for (int t = 0; t < nsteps; ++t) {
    const int cur = t & 1;
    const int kb = t * 64;
    if (t + 1 < nsteps) {
      const int kb2 = kb + 64;
#pragma unroll
      for (int i = 0; i < 2; ++i) {
        int r2 = srow + i * 8;
        int jg = jl ^ (r2 & 7);
        gload16(kg + (size_t)(kb2 + r2) * DMODEL + jg * 8, &Ks[cur ^ 1][(wid * 16 + i * 8) * 64]);
        gload16(vg + (size_t)r2 * SEQ + kb2 + jg * 8,      &Vs[cur ^ 1][(wid * 16 + i * 8) * 64]);
      }
    }
    // QK^T: S[16q][64key]
#pragma unroll
    for (int nb = 0; nb < 4; ++nb) {
      int key = nb * 16 + fr;
      const u16* kr = &Ks[cur][key * 64];
      bf16x8 k0 = *(const bf16x8*)&kr[((quad    ) ^ (key & 7)) * 8];
      bf16x8 k1 = *(const bf16x8*)&kr[((quad + 4) ^ (key & 7)) * 8];
      f32x4 s = {};
      s = MFMA16(aq0, k0, s);
      s = MFMA16(aq1, k1, s);
      sa[nb] = s;
    }
    if (causal && kb + 64 > qw) {      // wave-uniform branch; diagonal blocks only
#pragma unroll
      for (int nb = 0; nb < 4; ++nb) {
        int col = kb + nb * 16 + fr;
#pragma unroll
        for (int r = 0; r < 4; ++r)
          if (col > qw + quad * 4 + r) sa[nb][r] = -1e30f;
      }
    }
    float al[4];
#pragma unroll
    for (int r = 0; r < 4; ++r) {
      float s0 = sa[0][r], s1 = sa[1][r], s2 = sa[2][r], s3 = sa[3][r];
      float mx = fmaxf(fmaxf(s0, s1), fmaxf(s2, s3));
      mx = fmaxf(mx, __shfl_xor(mx, 1));
      mx = fmaxf(mx, __shfl_xor(mx, 2));
      mx = fmaxf(mx, __shfl_xor(mx, 4));
      mx = fmaxf(mx, __shfl_xor(mx, 8));
      float mnew = fmaxf(mrow[r], mx);
      float a = __builtin_amdgcn_exp2f(mrow[r] - mnew);
      mrow[r] = mnew;
      float p0 = __builtin_amdgcn_exp2f(s0 - mnew);
      float p1 = __builtin_amdgcn_exp2f(s1 - mnew);
      float p2 = __builtin_amdgcn_exp2f(s2 - mnew);
      float p3 = __builtin_amdgcn_exp2f(s3 - mnew);
      float ps = p0 + p1 + p2 + p3;
      ps += __shfl_xor(ps, 1);
      ps += __shfl_xor(ps, 2);
      ps += __shfl_xor(ps, 4);
      ps += __shfl_xor(ps, 8);
      lrow[r] = lrow[r] * a + ps;
      al[r] = a;
      int row = quad * 4 + r;
      u16* pr = &plds[wid][row * 64];
      pr[(((fr >> 3)    ) ^ (row & 7)) * 8 + (fr & 7)] = f2bf(p0);
      pr[(((fr >> 3) + 2) ^ (row & 7)) * 8 + (fr & 7)] = f2bf(p1);
      pr[(((fr >> 3) + 4) ^ (row & 7)) * 8 + (fr & 7)] = f2bf(p2);
      pr[(((fr >> 3) + 6) ^ (row & 7)) * 8 + (fr & 7)] = f2bf(p3);
    }
#pragma unroll
    for (int db = 0; db < 4; ++db) {
      oacc[db][0] *= al[0]; oacc[db][1] *= al[1];
      oacc[db][2] *= al[2]; oacc[db][3] *= al[3];
    }
    asm volatile("s_waitcnt lgkmcnt(0)" ::: "memory");
    bf16x8 pa0 = *(const bf16x8*)&plds[wid][fr * 64 + ((quad    ) ^ (fr & 7)) * 8];
    bf16x8 pa1 = *(const bf16x8*)&plds[wid][fr * 64 + ((quad + 4) ^ (fr & 7)) * 8];
#pragma unroll
    for (int db = 0; db < 4; ++db) {
      int d = db * 16 + fr;
      const u16* vr = &Vs[cur][d * 64];
      bf16x8 v0 = *(const bf16x8*)&vr[((quad    ) ^ (d & 7)) * 8];
      bf16x8 v1 = *(const bf16x8*)&vr[((quad + 4) ^ (d & 7)) * 8];
      oacc[db] = MFMA16(pa0, v0, oacc[db]);
      oacc[db] = MFMA16(pa1, v1, oacc[db]);
    }
    __syncthreads();   // buf[cur] reads done; buf[cur^1] staging drained
  }

  u16* op = O + (size_t)(b * SEQ + qw + quad * 4) * DMODEL + h * HDIM + fr;
#pragma unroll
  for (int r = 0; r < 4; ++r) {
    float inv = 1.0f / lrow[r];
#pragma unroll
    for (int db = 0; db < 4; ++db)
      op[(size_t)r * DMODEL + db * 16] = f2bf(oacc[db][r] * inv);
  }
}

// ---------------- launcher ----------------
extern "C" void kernel_launch(void* const* d_in, const int* in_sizes, int n_in,
                              void* d_out, int out_size, void* d_ws, size_t ws_size,
                              hipStream_t stream)
{
  const float* x   = (const float*)d_in[0];
  const float* ek  = (const float*)d_in[1];
  const float* ev  = (const float*)d_in[2];
  const float* Wq1 = (const float*)d_in[3];
  const float* bq1 = (const float*)d_in[4];
  const float* Wk1 = (const float*)d_in[5];
  const float* bk1 = (const float*)d_in[6];
  const float* Wv1 = (const float*)d_in[7];
  const float* bv1 = (const float*)d_in[8];
  const float* Wo1 = (const float*)d_in[9];
  const float* bo1 = (const float*)d_in[10];
  const float* Wq2 = (const float*)d_in[11];
  const float* bq2 = (const float*)d_in[12];
  const float* Wk2 = (const float*)d_in[13];
  const float* bk2 = (const float*)d_in[14];
  const float* Wv2 = (const float*)d_in[15];
  const float* bv2 = (const float*)d_in[16];
  const float* Wo2 = (const float*)d_in[17];
  const float* bo2 = (const float*)d_in[18];

  char* ws = (char*)d_ws;
  u16* wt  = (u16*)ws;
  u16* xb  = (u16*)(ws + (16u << 20));
  u16* ekb = (u16*)(ws + (32u << 20));
  u16* evb = (u16*)(ws + (48u << 20));
  u16* qb  = (u16*)(ws + (64u << 20));
  u16* kkb = (u16*)(ws + (80u << 20));
  u16* vtb = (u16*)(ws + (96u << 20));
  u16* hb  = (u16*)(ws + (112u << 20));
  u16* ob  = xb;   // x dead after layer-1 projections

  const int NW = DMODEL * DMODEL;
  const int n4 = MTOT * DMODEL / 4;
  const float qscale = 0.125f * 1.4426950408889634f;   // 1/sqrt(HD) * log2(e)

  pack_act<<<n4 / 256, 256, 0, stream>>>(x,  xb,  n4);
  pack_act<<<n4 / 256, 256, 0, stream>>>(ek, ekb, n4);
  pack_act<<<n4 / 256, 256, 0, stream>>>(ev, evb, n4);

  dim3 wg(16, 16);
  pack_w<<<wg, 256, 0, stream>>>(Wq1, wt + 0 * NW, 1);
  pack_w<<<wg, 256, 0, stream>>>(Wk1, wt + 1 * NW, 1);
  pack_w<<<wg, 256, 0, stream>>>(Wv1, wt + 2 * NW, 1);
  pack_w<<<wg, 256, 0, stream>>>(Wo1, wt + 3 * NW, 0);
  pack_w<<<wg, 256, 0, stream>>>(Wq2, wt + 4 * NW, 1);
  pack_w<<<wg, 256, 0, stream>>>(Wk2, wt + 5 * NW, 1);
  pack_w<<<wg, 256, 0, stream>>>(Wv2, wt + 6 * NW, 1);
  pack_w<<<wg, 256, 0, stream>>>(Wo2, wt + 7 * NW, 0);

  dim3 gg(DMODEL / 128, MTOT / 128);
  dim3 ag(SEQ / 64, BSZ * NHEAD);

  // layer 1: causal self-attention
  gemm_bt<0><<<gg, 256, 0, stream>>>(xb,  wt + 0 * NW, bq1, qb,  qscale);
  gemm_bt<0><<<gg, 256, 0, stream>>>(xb,  wt + 1 * NW, bk1, kkb, 1.0f);
  gemm_bt<1><<<gg, 256, 0, stream>>>(xb,  wt + 2 * NW, bv1, vtb, 1.0f);
  attn_kernel<<<ag, 256, 0, stream>>>(qb, kkb, vtb, ob, 1);
  gemm_bt<0><<<gg, 256, 0, stream>>>(ob,  wt + 3 * NW, bo1, hb,  1.0f);

  // layer 2: cross attention
  gemm_bt<0><<<gg, 256, 0, stream>>>(hb,  wt + 4 * NW, bq2, qb,  qscale);
  gemm_bt<0><<<gg, 256, 0, stream>>>(ekb, wt + 5 * NW, bk2, kkb, 1.0f);
  gemm_bt<1><<<gg, 256, 0, stream>>>(evb, wt + 6 * NW, bv2, vtb, 1.0f);
  attn_kernel<<<ag, 256, 0, stream>>>(qb, kkb, vtb, ob, 0);
  gemm_bt<2><<<gg, 256, 0, stream>>>(ob,  wt + 7 * NW, bo2, d_out, 1.0f);
}

// Round 3
// 501.431 us; speedup vs baseline: 2.4987x; 1.3422x over previous
//
#include <hip/hip_runtime.h>
#include <cstdint>

typedef unsigned short u16;
typedef unsigned int   u32;
typedef __attribute__((ext_vector_type(8))) short bf16x8;   // 8 bf16 = 4 VGPRs
typedef __attribute__((ext_vector_type(4))) float f32x4;

#define MFMA16(a,b,c) __builtin_amdgcn_mfma_f32_16x16x32_bf16((a),(b),(c),0,0,0)

#define BSZ    4
#define SEQ    2048
#define DMODEL 1024
#define NHEAD  16
#define HDIM   64
#define MTOT   (BSZ*SEQ)   // 8192

__device__ __forceinline__ u16 f2bf(float f) {
  u32 u = __float_as_uint(f);
  u32 r = u + 0x7fffu + ((u >> 16) & 1u);   // RNE
  return (u16)(r >> 16);
}

typedef __attribute__((address_space(1))) void g1v;
typedef __attribute__((address_space(3))) void l3v;
// async global->LDS, 16B/lane. LDS dest is wave-uniform base (HW adds lane*16B).
__device__ __forceinline__ void gload16(const void* g, void* l) {
  __builtin_amdgcn_global_load_lds((g1v*)(uintptr_t)g, (l3v*)(u32)(uintptr_t)l, 16, 0, 0);
}

// ---------------- pack: fp32 -> bf16 activations ----------------
__global__ void pack_act(const float* __restrict__ in, u16* __restrict__ out, int n4) {
  int i = blockIdx.x * blockDim.x + threadIdx.x;
  if (i >= n4) return;
  float4 v = ((const float4*)in)[i];
  u32 lo = (u32)f2bf(v.x) | ((u32)f2bf(v.y) << 16);
  u32 hi = (u32)f2bf(v.z) | ((u32)f2bf(v.w) << 16);
  ((uint2*)out)[i] = make_uint2(lo, hi);
}

// ---------------- pack: weights -> Bt[n][k] bf16 (transposed) ----------------
__global__ void pack_w(const float* __restrict__ src, u16* __restrict__ dst, int per_head) {
  __shared__ float tile[64][65];
  int kt = blockIdx.x * 64, nt = blockIdx.y * 64;
  int tx = threadIdx.x & 63, ty = threadIdx.x >> 6;
  for (int kk = ty; kk < 64; kk += 4) {
    int k = kt + kk, n = nt + tx;
    float v = per_head ? src[(size_t)(n >> 6) * (DMODEL * HDIM) + (size_t)k * HDIM + (n & 63)]
                       : src[(size_t)k * DMODEL + n];
    tile[kk][tx] = v;
  }
  __syncthreads();
  for (int nn = ty; nn < 64; nn += 4)
    dst[(size_t)(nt + nn) * DMODEL + kt + tx] = f2bf(tile[tx][nn]);
}

// ---------------- GEMM: C[M,N] = (A[M,K] @ Bt[N,K]^T + bias) * scale ----------------
// m97 structure: 128x128 tile, BK=32, 4 waves, global_load_lds(16B).
// EPI 0: bf16 [M][N]; 1: bf16 Vt[(b*16+h)*64+e][s]; 2: f32 [M][N]
template <int EPI>
__global__ __launch_bounds__(256, 2)
void gemm_bt(const u16* __restrict__ A, const u16* __restrict__ Bt,
             const float* __restrict__ bias, void* __restrict__ Cout, float scale)
{
  __shared__ u16 As[128 * 32];
  __shared__ u16 Bs[128 * 32];
  const int lane = threadIdx.x & 63, wid = threadIdx.x >> 6;
  const int m0 = blockIdx.y * 128, n0 = blockIdx.x * 128;

  const int srow = wid * 32 + (lane >> 2);
  const int scol = (lane & 3) * 8;
  const u16* gA = A  + (size_t)(m0 + srow) * DMODEL + scol;
  const u16* gB = Bt + (size_t)(n0 + srow) * DMODEL + scol;
  u16* lA0 = &As[(wid * 32) * 32];
  u16* lA1 = &As[(wid * 32 + 16) * 32];
  u16* lB0 = &Bs[(wid * 32) * 32];
  u16* lB1 = &Bs[(wid * 32 + 16) * 32];

  const int fr = lane & 15, quad = lane >> 4, fk = quad * 8;
  const int wr = (wid >> 1) * 64, wc = (wid & 1) * 64;

  f32x4 acc[4][4] = {};

  for (int kt = 0; kt < DMODEL / 32; ++kt) {
    __syncthreads();
    gload16(gA,               lA0);
    gload16(gA + 16 * DMODEL, lA1);
    gload16(gB,               lB0);
    gload16(gB + 16 * DMODEL, lB1);
    gA += 32; gB += 32;
    __syncthreads();

    bf16x8 af[4], bfr[4];
#pragma unroll
    for (int i = 0; i < 4; ++i) {
      af[i]  = *(const bf16x8*)&As[(wr + i * 16 + fr) * 32 + fk];
      bfr[i] = *(const bf16x8*)&Bs[(wc + i * 16 + fr) * 32 + fk];
    }
#pragma unroll
    for (int i = 0; i < 4; ++i)
#pragma unroll
      for (int j = 0; j < 4; ++j)
        acc[i][j] = MFMA16(af[i], bfr[j], acc[i][j]);
  }

  // C/D layout: col = lane&15, row = (lane>>4)*4 + reg
#pragma unroll
  for (int i = 0; i < 4; ++i) {
    int row0 = m0 + wr + i * 16 + quad * 4;
#pragma unroll
    for (int j = 0; j < 4; ++j) {
      int col = n0 + wc + j * 16 + fr;
      float bv = bias[col];
      float v0 = (acc[i][j][0] + bv) * scale, v1 = (acc[i][j][1] + bv) * scale;
      float v2 = (acc[i][j][2] + bv) * scale, v3 = (acc[i][j][3] + bv) * scale;
      if constexpr (EPI == 2) {
        float* C = (float*)Cout;
        C[(size_t)(row0 + 0) * DMODEL + col] = v0;
        C[(size_t)(row0 + 1) * DMODEL + col] = v1;
        C[(size_t)(row0 + 2) * DMODEL + col] = v2;
        C[(size_t)(row0 + 3) * DMODEL + col] = v3;
      } else if constexpr (EPI == 0) {
        u16* C = (u16*)Cout;
        C[(size_t)(row0 + 0) * DMODEL + col] = f2bf(v0);
        C[(size_t)(row0 + 1) * DMODEL + col] = f2bf(v1);
        C[(size_t)(row0 + 2) * DMODEL + col] = f2bf(v2);
        C[(size_t)(row0 + 3) * DMODEL + col] = f2bf(v3);
      } else {
        u16* C = (u16*)Cout;
        int bi = row0 >> 11, s = row0 & 2047;
        size_t vtr = ((size_t)(bi * NHEAD + (col >> 6)) * HDIM + (col & 63)) * SEQ + s;
        *(uint2*)&C[vtr] = make_uint2((u32)f2bf(v0) | ((u32)f2bf(v1) << 16),
                                      (u32)f2bf(v2) | ((u32)f2bf(v3) << 16));
      }
    }
  }
}

// ---------------- flash attention v3 ----------------
// grid flattened (SEQ/64 * B*H); XCD-swizzled so all q-blocks of one head share an XCD's L2.
// 4 waves/block; wave owns 16 q-rows. KVBLK=64 double-buffered via global_load_lds,
// 16B-chunk XOR swizzle (involution). Q pre-scaled by 0.125*log2e; exp2-domain softmax.
// T13 defer-max: skip max-reduce + rescale when no lane's tile-max exceeds m+11.
// Row-sum kept as per-lane partials, reduced once at the end.
__global__ __launch_bounds__(256, 4)
void attn_kernel(const u16* __restrict__ Q, const u16* __restrict__ K,
                 const u16* __restrict__ Vt, u16* __restrict__ O, int causal)
{
  __shared__ u16 Ks[2][64 * 64];   // [key][dim], swizzled
  __shared__ u16 Vs[2][64 * 64];   // [d][s_local], swizzled
  __shared__ u16 plds[4][16 * 64]; // per-wave P [q][key], swizzled
  const int lane = threadIdx.x & 63, wid = threadIdx.x >> 6;
  const int fr = lane & 15, quad = lane >> 4;

  // XCD swizzle: flat = [bh_hi:3][qb:5][xcd:3]; bh = bh_hi*8 + xcd.
  // Per XCD: 32 consecutive q-blocks of the same head (K/V panel L2-resident).
  // Heavy q-blocks first (helps causal makespan).
  const int flat = blockIdx.x;
  const int bh = ((flat >> 8) << 3) | (flat & 7);
  const int qb = 31 - ((flat >> 3) & 31);
  const int b = bh >> 4, h = bh & 15;
  const int q0 = qb * 64;
  const int qw = q0 + wid * 16;

  const u16* qp = Q + (size_t)(b * SEQ + qw + fr) * DMODEL + h * HDIM + quad * 8;
  bf16x8 aq0 = *(const bf16x8*)qp;
  bf16x8 aq1 = *(const bf16x8*)(qp + 32);

  const int srow = wid * 16 + (lane >> 3);  // + i*8
  const int jl = lane & 7;
  const u16* kg = K + (size_t)b * SEQ * DMODEL + h * HDIM;
  const u16* vg = Vt + (size_t)bh * HDIM * SEQ;

  f32x4 oacc[4] = {};
  f32x4 sa[4];
  float mrow[4]  = {-1e30f, -1e30f, -1e30f, -1e30f};
  float lpart[4] = {0.f, 0.f, 0.f, 0.f};

  const int nsteps = (causal ? (q0 + 64) : SEQ) >> 6;

#pragma unroll
  for (int i = 0; i < 2; ++i) {
    int r2 = srow + i * 8;
    int jg = jl ^ (r2 & 7);
    gload16(kg + (size_t)r2 * DMODEL + jg * 8, &Ks[0][(wid * 16 + i * 8) * 64]);
    gload16(vg + (size_t)r2 * SEQ + jg * 8,    &Vs[0][(wid * 16 + i * 8) * 64]);
  }
  __syncthreads();

  for (int t = 0; t < nsteps; ++t) {
    const int cur = t & 1;
    const int kb = t * 64;
    if (t + 1 < nsteps) {
      const int kb2 = kb + 64;
#pragma unroll
      for (int i = 0; i < 2; ++i) {
        int r2 = srow + i * 8;
        int jg = jl ^ (r2 & 7);
        gload16(kg + (size_t)(kb2 + r2) * DMODEL + jg * 8, &Ks[cur ^ 1][(wid * 16 + i * 8) * 64]);
        gload16(vg + (size_t)r2 * SEQ + kb2 + jg * 8,      &Vs[cur ^ 1][(wid * 16 + i * 8) * 64]);
      }
    }
    // QK^T: S[16q][64key]
    __builtin_amdgcn_s_setprio(1);
#pragma unroll
    for (int nb = 0; nb < 4; ++nb) {
      int key = nb * 16 + fr;
      const u16* kr = &Ks[cur][key * 64];
      bf16x8 k0 = *(const bf16x8*)&kr[((quad    ) ^ (key & 7)) * 8];
      bf16x8 k1 = *(const bf16x8*)&kr[((quad + 4) ^ (key & 7)) * 8];
      f32x4 s = {};
      s = MFMA16(aq0, k0, s);
      s = MFMA16(aq1, k1, s);
      sa[nb] = s;
    }
    __builtin_amdgcn_s_setprio(0);
    if (causal && kb + 64 > qw) {      // wave-uniform; diagonal blocks only
#pragma unroll
      for (int nb = 0; nb < 4; ++nb) {
        int col = kb + nb * 16 + fr;
#pragma unroll
        for (int r = 0; r < 4; ++r)
          if (col > qw + quad * 4 + r) sa[nb][r] = -1e30f;
      }
    }

    // ---- softmax: defer-max fast path ----
    float lm[4];
#pragma unroll
    for (int r = 0; r < 4; ++r)
      lm[r] = fmaxf(fmaxf(sa[0][r], sa[1][r]), fmaxf(sa[2][r], sa[3][r]));
    int ok = (lm[0] <= mrow[0] + 11.f) & (lm[1] <= mrow[1] + 11.f) &
             (lm[2] <= mrow[2] + 11.f) & (lm[3] <= mrow[3] + 11.f);
    if (!__all(ok)) {
#pragma unroll
      for (int r = 0; r < 4; ++r) {
        float mx = lm[r];
        mx = fmaxf(mx, __shfl_xor(mx, 1));
        mx = fmaxf(mx, __shfl_xor(mx, 2));
        mx = fmaxf(mx, __shfl_xor(mx, 4));
        mx = fmaxf(mx, __shfl_xor(mx, 8));
        float mnew = fmaxf(mrow[r], mx);
        float a = __builtin_amdgcn_exp2f(mrow[r] - mnew);
        mrow[r] = mnew;
        lpart[r] *= a;
        oacc[0][r] *= a; oacc[1][r] *= a; oacc[2][r] *= a; oacc[3][r] *= a;
      }
    }
#pragma unroll
    for (int r = 0; r < 4; ++r) {
      float p0 = __builtin_amdgcn_exp2f(sa[0][r] - mrow[r]);
      float p1 = __builtin_amdgcn_exp2f(sa[1][r] - mrow[r]);
      float p2 = __builtin_amdgcn_exp2f(sa[2][r] - mrow[r]);
      float p3 = __builtin_amdgcn_exp2f(sa[3][r] - mrow[r]);
      lpart[r] += (p0 + p1) + (p2 + p3);
      int row = quad * 4 + r;
      u16* pr = &plds[wid][row * 64];
      pr[(((fr >> 3)    ) ^ (row & 7)) * 8 + (fr & 7)] = f2bf(p0);
      pr[(((fr >> 3) + 2) ^ (row & 7)) * 8 + (fr & 7)] = f2bf(p1);
      pr[(((fr >> 3) + 4) ^ (row & 7)) * 8 + (fr & 7)] = f2bf(p2);
      pr[(((fr >> 3) + 6) ^ (row & 7)) * 8 + (fr & 7)] = f2bf(p3);
    }
    asm volatile("s_waitcnt lgkmcnt(0)" ::: "memory");
    bf16x8 pa0 = *(const bf16x8*)&plds[wid][fr * 64 + ((quad    ) ^ (fr & 7)) * 8];
    bf16x8 pa1 = *(const bf16x8*)&plds[wid][fr * 64 + ((quad + 4) ^ (fr & 7)) * 8];
    __builtin_amdgcn_s_setprio(1);
#pragma unroll
    for (int db = 0; db < 4; ++db) {
      int d = db * 16 + fr;
      const u16* vr = &Vs[cur][d * 64];
      bf16x8 v0 = *(const bf16x8*)&vr[((quad    ) ^ (d & 7)) * 8];
      bf16x8 v1 = *(const bf16x8*)&vr[((quad + 4) ^ (d & 7)) * 8];
      oacc[db] = MFMA16(pa0, v0, oacc[db]);
      oacc[db] = MFMA16(pa1, v1, oacc[db]);
    }
    __builtin_amdgcn_s_setprio(0);
    __syncthreads();   // buf[cur] reads done; buf[cur^1] staging drained
  }

  u16* op = O + (size_t)(b * SEQ + qw + quad * 4) * DMODEL + h * HDIM + fr;
#pragma unroll
  for (int r = 0; r < 4; ++r) {
    float s = lpart[r];
    s += __shfl_xor(s, 1);
    s += __shfl_xor(s, 2);
    s += __shfl_xor(s, 4);
    s += __shfl_xor(s, 8);
    float inv = 1.0f / s;
#pragma unroll
    for (int db = 0; db < 4; ++db)
      op[(size_t)r * DMODEL + db * 16] = f2bf(oacc[db][r] * inv);
  }
}

// ---------------- launcher ----------------
extern "C" void kernel_launch(void* const* d_in, const int* in_sizes, int n_in,
                              void* d_out, int out_size, void* d_ws, size_t ws_size,
                              hipStream_t stream)
{
  const float* x   = (const float*)d_in[0];
  const float* ek  = (const float*)d_in[1];
  const float* ev  = (const float*)d_in[2];
  const float* Wq1 = (const float*)d_in[3];
  const float* bq1 = (const float*)d_in[4];
  const float* Wk1 = (const float*)d_in[5];
  const float* bk1 = (const float*)d_in[6];
  const float* Wv1 = (const float*)d_in[7];
  const float* bv1 = (const float*)d_in[8];
  const float* Wo1 = (const float*)d_in[9];
  const float* bo1 = (const float*)d_in[10];
  const float* Wq2 = (const float*)d_in[11];
  const float* bq2 = (const float*)d_in[12];
  const float* Wk2 = (const float*)d_in[13];
  const float* bk2 = (const float*)d_in[14];
  const float* Wv2 = (const float*)d_in[15];
  const float* bv2 = (const float*)d_in[16];
  const float* Wo2 = (const float*)d_in[17];
  const float* bo2 = (const float*)d_in[18];

  char* ws = (char*)d_ws;
  u16* wt  = (u16*)ws;
  u16* xb  = (u16*)(ws + (16u << 20));
  u16* ekb = (u16*)(ws + (32u << 20));
  u16* evb = (u16*)(ws + (48u << 20));
  u16* qb  = (u16*)(ws + (64u << 20));
  u16* kkb = (u16*)(ws + (80u << 20));
  u16* vtb = (u16*)(ws + (96u << 20));
  u16* hb  = (u16*)(ws + (112u << 20));
  u16* ob  = xb;   // x dead after layer-1 projections

  const int NW = DMODEL * DMODEL;
  const int n4 = MTOT * DMODEL / 4;
  const float qscale = 0.125f * 1.4426950408889634f;   // 1/sqrt(HD) * log2(e)

  pack_act<<<n4 / 256, 256, 0, stream>>>(x,  xb,  n4);
  pack_act<<<n4 / 256, 256, 0, stream>>>(ek, ekb, n4);
  pack_act<<<n4 / 256, 256, 0, stream>>>(ev, evb, n4);

  dim3 wg(16, 16);
  pack_w<<<wg, 256, 0, stream>>>(Wq1, wt + 0 * NW, 1);
  pack_w<<<wg, 256, 0, stream>>>(Wk1, wt + 1 * NW, 1);
  pack_w<<<wg, 256, 0, stream>>>(Wv1, wt + 2 * NW, 1);
  pack_w<<<wg, 256, 0, stream>>>(Wo1, wt + 3 * NW, 0);
  pack_w<<<wg, 256, 0, stream>>>(Wq2, wt + 4 * NW, 1);
  pack_w<<<wg, 256, 0, stream>>>(Wk2, wt + 5 * NW, 1);
  pack_w<<<wg, 256, 0, stream>>>(Wv2, wt + 6 * NW, 1);
  pack_w<<<wg, 256, 0, stream>>>(Wo2, wt + 7 * NW, 0);

  dim3 gg(DMODEL / 128, MTOT / 128);
  const int ablocks = (SEQ / 64) * BSZ * NHEAD;   // 2048, flattened + swizzled

  // layer 1: causal self-attention
  gemm_bt<0><<<gg, 256, 0, stream>>>(xb,  wt + 0 * NW, bq1, qb,  qscale);
  gemm_bt<0><<<gg, 256, 0, stream>>>(xb,  wt + 1 * NW, bk1, kkb, 1.0f);
  gemm_bt<1><<<gg, 256, 0, stream>>>(xb,  wt + 2 * NW, bv1, vtb, 1.0f);
  attn_kernel<<<ablocks, 256, 0, stream>>>(qb, kkb, vtb, ob, 1);
  gemm_bt<0><<<gg, 256, 0, stream>>>(ob,  wt + 3 * NW, bo1, hb,  1.0f);

  // layer 2: cross attention
  gemm_bt<0><<<gg, 256, 0, stream>>>(hb,  wt + 4 * NW, bq2, qb,  qscale);
  gemm_bt<0><<<gg, 256, 0, stream>>>(ekb, wt + 5 * NW, bk2, kkb, 1.0f);
  gemm_bt<1><<<gg, 256, 0, stream>>>(evb, wt + 6 * NW, bv2, vtb, 1.0f);
  attn_kernel<<<ablocks, 256, 0, stream>>>(qb, kkb, vtb, ob, 0);
  gemm_bt<2><<<gg, 256, 0, stream>>>(ob,  wt + 7 * NW, bo2, d_out, 1.0f);
}